// Round 1
// baseline (699.139 us; speedup 1.0000x reference)
//
#include <hip/hip_runtime.h>

#define DEV __device__ __forceinline__

using bf16x8 = __attribute__((ext_vector_type(8))) short;
using f32x4  = __attribute__((ext_vector_type(4))) float;
using u16 = unsigned short;

constexpr int S_   = 2048;
constexpr int D_   = 1024;
constexpr int M_   = 4096;   // B*S tokens
constexpr int WIN_ = 256;
constexpr float SCALE_ = 0.125f;

typedef const __attribute__((address_space(1))) void* gptr_t;
typedef __attribute__((address_space(3))) void* lptr_t;

DEV u16 f2bf(float f) {
  unsigned u = __builtin_bit_cast(unsigned, f);
  return (u16)((u + 0x7fffu + ((u >> 16) & 1u)) >> 16);
}
DEV float bf2f(u16 b) {
  unsigned u = ((unsigned)b) << 16;
  return __builtin_bit_cast(float, u);
}

// ---------------- transpose + bf16 cast:  src (K x N) f32  ->  dst (N x K) bf16
__global__ __launch_bounds__(256) void transpose_cast(const float* __restrict__ src, int K, int N,
                                                      u16* __restrict__ dst) {
  __shared__ float tile[32][33];
  int n0 = blockIdx.x * 32, k0 = blockIdx.y * 32;
  int tx = threadIdx.x & 31, ty = threadIdx.x >> 5;   // ty 0..7
#pragma unroll
  for (int p = 0; p < 4; ++p)
    tile[ty + p * 8][tx] = src[(size_t)(k0 + ty + p * 8) * N + n0 + tx];
  __syncthreads();
#pragma unroll
  for (int p = 0; p < 4; ++p)
    dst[(size_t)(n0 + ty + p * 8) * K + k0 + tx] = f2bf(tile[tx][ty + p * 8]);
}

// ---------------- adaLN modulation vector: mod[b][n] = (silu(cond) @ W)[n] + bias[n]
__global__ __launch_bounds__(256) void adaln_mod(const float* __restrict__ cond,
                                                 const float* __restrict__ W,
                                                 const float* __restrict__ bias,
                                                 float* __restrict__ modout) {
  int b = blockIdx.y;
  int n = blockIdx.x * 256 + threadIdx.x;
  __shared__ float sc[1024];
  for (int i = threadIdx.x; i < 1024; i += 256) {
    float c = cond[b * 1024 + i];
    sc[i] = c / (1.f + expf(-c));
  }
  __syncthreads();
  float acc = bias[n];
#pragma unroll 4
  for (int c = 0; c < 1024; ++c) acc += sc[c] * W[(size_t)c * 3072 + n];
  modout[b * 3072 + n] = acc;
}

// ---------------- LayerNorm + (1+scale)*x + shift -> bf16
__global__ __launch_bounds__(256) void ln_mod_kernel(const float* __restrict__ x,
                                                     const float* __restrict__ modset,
                                                     u16* __restrict__ out) {
  int m = blockIdx.x;
  int b = m >> 11;
  int tid = threadIdx.x;
  const float4* row = reinterpret_cast<const float4*>(x + (size_t)m * D_);
  float4 v = row[tid];
  float s = v.x + v.y + v.z + v.w;
  float ss = v.x * v.x + v.y * v.y + v.z * v.z + v.w * v.w;
#pragma unroll
  for (int o = 1; o < 64; o <<= 1) { s += __shfl_xor(s, o); ss += __shfl_xor(ss, o); }
  __shared__ float rs[4], rq[4];
  if ((tid & 63) == 0) { rs[tid >> 6] = s; rq[tid >> 6] = ss; }
  __syncthreads();
  s = rs[0] + rs[1] + rs[2] + rs[3];
  ss = rq[0] + rq[1] + rq[2] + rq[3];
  float mu = s * (1.f / D_);
  float rinv = rsqrtf(ss * (1.f / D_) - mu * mu + 1e-5f);
  int n = tid * 4;
  const float* mb = modset + b * 3072;
  float4 sh = *reinterpret_cast<const float4*>(mb + n);
  float4 sc = *reinterpret_cast<const float4*>(mb + 1024 + n);
  ushort4 o4;
  o4.x = f2bf((v.x - mu) * rinv * (1.f + sc.x) + sh.x);
  o4.y = f2bf((v.y - mu) * rinv * (1.f + sc.y) + sh.y);
  o4.z = f2bf((v.z - mu) * rinv * (1.f + sc.z) + sh.z);
  o4.w = f2bf((v.w - mu) * rinv * (1.f + sc.w) + sh.w);
  *reinterpret_cast<ushort4*>(out + (size_t)m * D_ + n) = o4;
}

// ---------------- RoPE in-place on q,k planes of qkv (M x 3072) f32
__global__ __launch_bounds__(256) void rope_kernel(float* __restrict__ qkv,
                                                   const float* __restrict__ cs,
                                                   const float* __restrict__ sn) {
  int idx = blockIdx.x * 256 + threadIdx.x;   // M*16*32
  int i = idx & 31;
  int h = (idx >> 5) & 15;
  int m = idx >> 9;
  int s = m & (S_ - 1);
  float c = cs[s * 32 + i], si = sn[s * 32 + i];
  float2* qp = reinterpret_cast<float2*>(qkv + (size_t)m * 3072 + h * 64 + 2 * i);
  float2* kp = reinterpret_cast<float2*>(qkv + (size_t)m * 3072 + 1024 + h * 64 + 2 * i);
  float2 q = *qp, k = *kp;
  *qp = make_float2(q.x * c - q.y * si, q.x * si + q.y * c);
  *kp = make_float2(k.x * c - k.y * si, k.x * si + k.y * c);
}

// ---------------- sliding-window attention (online softmax), writes bf16 (M x 1024)
__global__ __launch_bounds__(256) void attn_kernel(const float* __restrict__ qkv,
                                                   u16* __restrict__ out) {
  int q0 = blockIdx.x * 32;
  int h = blockIdx.y;
  int b = blockIdx.z;
  __shared__ float Qs[32][68];
  __shared__ float Ks[8][68];
  __shared__ float Vs[8][68];
  __shared__ float Ps[32][8];
  int tid = threadIdx.x;
  for (int t = tid; t < 32 * 64; t += 256) {
    int r = t >> 6, d = t & 63;
    Qs[r][d] = qkv[(size_t)(b * S_ + q0 + r) * 3072 + h * 64 + d];
  }
  int qi = tid >> 3, jj = tid & 7;
  int iq = q0 + qi;
  float mrow = -__builtin_inff(), lrow = 0.f;
  float acc[8] = {0, 0, 0, 0, 0, 0, 0, 0};
  int jstart = q0 - WIN_; if (jstart < 0) jstart = 0;
  int jend = q0 + 31;
  __syncthreads();
  for (int jb = jstart; jb <= jend; jb += 8) {
    __syncthreads();   // previous chunk's PV done before restaging
    for (int t = tid; t < 8 * 64; t += 256) {
      int r = t >> 6, d = t & 63;
      int j = jb + r;
      float kv = 0.f, vv = 0.f;
      if (j < S_) {
        size_t base = (size_t)(b * S_ + j) * 3072 + h * 64 + d;
        kv = qkv[base + 1024];
        vv = qkv[base + 2048];
      }
      Ks[r][d] = kv;
      Vs[r][d] = vv;
    }
    __syncthreads();
    int j = jb + jj;
    bool valid = (j <= iq) && (iq - j <= WIN_);
    float scv = -__builtin_inff();
    if (valid) {
      const float4* qp = reinterpret_cast<const float4*>(&Qs[qi][0]);
      const float4* kp = reinterpret_cast<const float4*>(&Ks[jj][0]);
      float dot = 0.f;
#pragma unroll
      for (int d = 0; d < 16; ++d) {
        float4 a = qp[d], bb = kp[d];
        dot += a.x * bb.x + a.y * bb.y + a.z * bb.z + a.w * bb.w;
      }
      scv = dot * SCALE_;
    }
    float cm = scv;
    cm = fmaxf(cm, __shfl_xor(cm, 1));
    cm = fmaxf(cm, __shfl_xor(cm, 2));
    cm = fmaxf(cm, __shfl_xor(cm, 4));
    float mnew = fmaxf(mrow, cm);
    float e = valid ? __expf(scv - mnew) : 0.f;
    float r = (mnew == -__builtin_inff()) ? 0.f : __expf(mrow - mnew);
    float esum = e;
    esum += __shfl_xor(esum, 1);
    esum += __shfl_xor(esum, 2);
    esum += __shfl_xor(esum, 4);
    lrow = lrow * r + esum;
    mrow = mnew;
    Ps[qi][jj] = e;
#pragma unroll
    for (int k = 0; k < 8; ++k) acc[k] *= r;
#pragma unroll
    for (int t = 0; t < 8; ++t) {
      float p = Ps[qi][t];
#pragma unroll
      for (int k = 0; k < 8; ++k) acc[k] += p * Vs[t][jj + 8 * k];
    }
  }
  float inv = 1.f / lrow;
  size_t ob = (size_t)(b * S_ + iq) * D_ + h * 64 + jj;
#pragma unroll
  for (int k = 0; k < 8; ++k) out[ob + 8 * k] = f2bf(acc[k] * inv);
}

// ---------------- swiglu: silu(g[:, :4096]) * g[:, 4096:] -> bf16 (M x 4096)
__global__ __launch_bounds__(256) void swiglu_kernel(const u16* __restrict__ g,
                                                     u16* __restrict__ out) {
  int idx = blockIdx.x * 256 + threadIdx.x;   // M*1024 quads
  int m = idx >> 10, n4 = (idx & 1023) * 4;
  const u16* gr = g + (size_t)m * 8192;
  ushort4 a = *reinterpret_cast<const ushort4*>(gr + n4);
  ushort4 c = *reinterpret_cast<const ushort4*>(gr + 4096 + n4);
  ushort4 o;
  float af;
  af = bf2f(a.x); o.x = f2bf(af / (1.f + __expf(-af)) * bf2f(c.x));
  af = bf2f(a.y); o.y = f2bf(af / (1.f + __expf(-af)) * bf2f(c.y));
  af = bf2f(a.z); o.z = f2bf(af / (1.f + __expf(-af)) * bf2f(c.z));
  af = bf2f(a.w); o.w = f2bf(af / (1.f + __expf(-af)) * bf2f(c.w));
  *reinterpret_cast<ushort4*>(out + (size_t)m * 4096 + n4) = o;
}

// ---------------- bf16 MFMA GEMM:  C(MxN) = A(MxK) @ Bt(NxK)^T, 128x128 tile, BK=32
DEV bf16x8 read_frag(const u16* tile, int r16, int lane) {
  int r = r16 + (lane & 15);
  int cb = ((lane >> 4) << 4) ^ (((r >> 1) & 3) << 4);
  return *reinterpret_cast<const bf16x8*>(reinterpret_cast<const char*>(tile) + r * 64 + cb);
}

DEV void stage_tile(const u16* __restrict__ src, int ld, int rowBase, int kBase,
                    u16* tile, int tid) {
#pragma unroll
  for (int c = 0; c < 2; ++c) {
    int row = c * 64 + (tid >> 2);
    int cbs = ((tid & 3) << 4) ^ (((row >> 1) & 3) << 4);
    const char* g = reinterpret_cast<const char*>(src + (size_t)(rowBase + row) * ld + kBase) + cbs;
    char* l = reinterpret_cast<char*>(tile) + c * 4096 + (tid >> 6) * 1024;
    __builtin_amdgcn_global_load_lds((gptr_t)g, (lptr_t)l, 16, 0, 0);
  }
}

template <int EPI>
__global__ __launch_bounds__(256, 2) void gemm_bt(const u16* __restrict__ A,
                                                  const u16* __restrict__ Bt,
                                                  int M, int N, int K,
                                                  void* __restrict__ Cv,
                                                  const float* __restrict__ gate,
                                                  const float* __restrict__ resid) {
  __shared__ __align__(16) u16 lds[2][2][4096];
  int tid = threadIdx.x;
  int lane = tid & 63;
  int w = tid >> 6;
  int wr = w >> 1, wc = w & 1;
  int m0 = blockIdx.y * 128;
  int n0 = blockIdx.x * 128;
  f32x4 zero = {0.f, 0.f, 0.f, 0.f};
  f32x4 acc[4][4];
#pragma unroll
  for (int i = 0; i < 4; ++i)
#pragma unroll
    for (int j = 0; j < 4; ++j) acc[i][j] = zero;
  stage_tile(A, K, m0, 0, &lds[0][0][0], tid);
  stage_tile(Bt, K, n0, 0, &lds[0][1][0], tid);
  __syncthreads();
  int nt = K >> 5;
  int cur = 0;
  for (int t = 0; t < nt; ++t) {
    if (t + 1 < nt) {
      stage_tile(A, K, m0, (t + 1) << 5, &lds[cur ^ 1][0][0], tid);
      stage_tile(Bt, K, n0, (t + 1) << 5, &lds[cur ^ 1][1][0], tid);
    }
    bf16x8 af[4], bfr[4];
#pragma unroll
    for (int i = 0; i < 4; ++i) af[i] = read_frag(&lds[cur][0][0], wr * 64 + i * 16, lane);
#pragma unroll
    for (int i = 0; i < 4; ++i) bfr[i] = read_frag(&lds[cur][1][0], wc * 64 + i * 16, lane);
#pragma unroll
    for (int i = 0; i < 4; ++i)
#pragma unroll
      for (int j = 0; j < 4; ++j)
        acc[i][j] = __builtin_amdgcn_mfma_f32_16x16x32_bf16(af[i], bfr[j], acc[i][j], 0, 0, 0);
    __syncthreads();
    cur ^= 1;
  }
  int colB = n0 + wc * 64 + (lane & 15);
  int rowB = m0 + wr * 64 + ((lane >> 4) << 2);
#pragma unroll
  for (int i = 0; i < 4; ++i) {
#pragma unroll
    for (int j = 0; j < 4; ++j) {
      int col = colB + j * 16;
#pragma unroll
      for (int jr = 0; jr < 4; ++jr) {
        int row = rowB + i * 16 + jr;
        float v = acc[i][j][jr];
        size_t idx = (size_t)row * N + col;
        if constexpr (EPI == 0) {
          reinterpret_cast<float*>(Cv)[idx] = v;
        } else if constexpr (EPI == 1) {
          int bb = row >> 11;
          reinterpret_cast<float*>(Cv)[idx] = resid[idx] + gate[bb * 3072 + col] * v;
        } else {
          reinterpret_cast<u16*>(Cv)[idx] = f2bf(v);
        }
      }
    }
  }
}

extern "C" void kernel_launch(void* const* d_in, const int* in_sizes, int n_in,
                              void* d_out, int out_size, void* d_ws, size_t ws_size,
                              hipStream_t stream) {
  const float* x    = (const float*)d_in[0];
  const float* rc   = (const float*)d_in[1];
  const float* rs   = (const float*)d_in[2];
  const float* cond = (const float*)d_in[3];
  const float* wq   = (const float*)d_in[4];
  const float* wk   = (const float*)d_in[5];
  const float* wv   = (const float*)d_in[6];
  const float* wo   = (const float*)d_in[7];
  const float* aaw  = (const float*)d_in[8];
  const float* aab  = (const float*)d_in[9];
  const float* afw  = (const float*)d_in[10];
  const float* afb  = (const float*)d_in[11];
  const float* w1   = (const float*)d_in[12];
  const float* w3   = (const float*)d_in[13];   // dict order: w1, w3, w2
  const float* w2   = (const float*)d_in[14];
  float* out = (float*)d_out;
  char* ws = (char*)d_ws;

  u16*   wt_qkv = (u16*)  (ws + 0);           // 3072x1024 bf16
  u16*   wt_o   = (u16*)  (ws + 6291456);     // 1024x1024
  u16*   wt_13  = (u16*)  (ws + 8388608);     // 8192x1024
  u16*   wt_2   = (u16*)  (ws + 25165824);    // 1024x4096
  float* modf   = (float*)(ws + 33554432);    // [2 sets][B][3072]
  u16*   norm_b = (u16*)  (ws + 33603584);    // M x 1024 bf16 (reused for both LNs)
  u16*   attn_b = (u16*)  (ws + 41992192);    // M x 1024 bf16
  float* qkv_f  = (float*)(ws + 50380800);    // M x 3072 f32
  u16*   g_bf   = (u16*)  (ws + 50380800);    // M x 8192 bf16 (aliases qkv: disjoint live range)
  float* hbuf   = (float*)(ws + 117489664);   // M x 1024 f32
  u16*   swig_b = (u16*)  (ws + 134266880);   // M x 4096 bf16

  adaln_mod<<<dim3(12, 2), 256, 0, stream>>>(cond, aaw, aab, modf);
  adaln_mod<<<dim3(12, 2), 256, 0, stream>>>(cond, afw, afb, modf + 6144);
  transpose_cast<<<dim3(32, 32), 256, 0, stream>>>(wq, 1024, 1024, wt_qkv);
  transpose_cast<<<dim3(32, 32), 256, 0, stream>>>(wk, 1024, 1024, wt_qkv + 1048576);
  transpose_cast<<<dim3(32, 32), 256, 0, stream>>>(wv, 1024, 1024, wt_qkv + 2097152);
  transpose_cast<<<dim3(32, 32), 256, 0, stream>>>(wo, 1024, 1024, wt_o);
  transpose_cast<<<dim3(128, 32), 256, 0, stream>>>(w1, 1024, 4096, wt_13);
  transpose_cast<<<dim3(128, 32), 256, 0, stream>>>(w3, 1024, 4096, wt_13 + 4194304);
  transpose_cast<<<dim3(32, 128), 256, 0, stream>>>(w2, 4096, 1024, wt_2);

  ln_mod_kernel<<<4096, 256, 0, stream>>>(x, modf, norm_b);
  gemm_bt<0><<<dim3(24, 32), 256, 0, stream>>>(norm_b, wt_qkv, M_, 3072, 1024, qkv_f, nullptr, nullptr);
  rope_kernel<<<8192, 256, 0, stream>>>(qkv_f, rc, rs);
  attn_kernel<<<dim3(64, 16, 2), 256, 0, stream>>>(qkv_f, attn_b);
  gemm_bt<1><<<dim3(8, 32), 256, 0, stream>>>(attn_b, wt_o, M_, 1024, 1024, hbuf, modf + 2048, x);
  ln_mod_kernel<<<4096, 256, 0, stream>>>(hbuf, modf + 6144, norm_b);
  gemm_bt<2><<<dim3(64, 32), 256, 0, stream>>>(norm_b, wt_13, M_, 8192, 1024, g_bf, nullptr, nullptr);
  swiglu_kernel<<<16384, 256, 0, stream>>>(g_bf, swig_b);
  gemm_bt<1><<<dim3(8, 32), 256, 0, stream>>>(swig_b, wt_2, M_, 1024, 4096, out, modf + 6144 + 2048, hbuf);
}

// Round 2
// 525.489 us; speedup vs baseline: 1.3305x; 1.3305x over previous
//
#include <hip/hip_runtime.h>

#define DEV __device__ __forceinline__

using bf16x8 = __attribute__((ext_vector_type(8))) short;
using f32x4  = __attribute__((ext_vector_type(4))) float;
using u16 = unsigned short;

constexpr int S_   = 2048;
constexpr int D_   = 1024;
constexpr int M_   = 4096;   // B*S tokens
constexpr int WIN_ = 256;
constexpr float SCALE_ = 0.125f;

typedef const __attribute__((address_space(1))) void* gptr_t;
typedef __attribute__((address_space(3))) void* lptr_t;

DEV u16 f2bf(float f) {
  unsigned u = __builtin_bit_cast(unsigned, f);
  return (u16)((u + 0x7fffu + ((u >> 16) & 1u)) >> 16);
}
DEV float bf2f(u16 b) {
  unsigned u = ((unsigned)b) << 16;
  return __builtin_bit_cast(float, u);
}

// ---------------- transpose + bf16 cast:  src (K x N) f32  ->  dst (N x K) bf16
__global__ __launch_bounds__(256) void transpose_cast(const float* __restrict__ src, int K, int N,
                                                      u16* __restrict__ dst) {
  __shared__ float tile[32][33];
  int n0 = blockIdx.x * 32, k0 = blockIdx.y * 32;
  int tx = threadIdx.x & 31, ty = threadIdx.x >> 5;   // ty 0..7
#pragma unroll
  for (int p = 0; p < 4; ++p)
    tile[ty + p * 8][tx] = src[(size_t)(k0 + ty + p * 8) * N + n0 + tx];
  __syncthreads();
#pragma unroll
  for (int p = 0; p < 4; ++p)
    dst[(size_t)(n0 + ty + p * 8) * K + k0 + tx] = f2bf(tile[tx][ty + p * 8]);
}

// ---------------- adaLN modulation vector
__global__ __launch_bounds__(256) void adaln_mod(const float* __restrict__ cond,
                                                 const float* __restrict__ W,
                                                 const float* __restrict__ bias,
                                                 float* __restrict__ modout) {
  int b = blockIdx.y;
  int n = blockIdx.x * 256 + threadIdx.x;
  __shared__ float sc[1024];
  for (int i = threadIdx.x; i < 1024; i += 256) {
    float c = cond[b * 1024 + i];
    sc[i] = c / (1.f + expf(-c));
  }
  __syncthreads();
  float acc = bias[n];
#pragma unroll 4
  for (int c = 0; c < 1024; ++c) acc += sc[c] * W[(size_t)c * 3072 + n];
  modout[b * 3072 + n] = acc;
}

// ---------------- LayerNorm + (1+scale)*x + shift -> bf16
__global__ __launch_bounds__(256) void ln_mod_kernel(const float* __restrict__ x,
                                                     const float* __restrict__ modset,
                                                     u16* __restrict__ out) {
  int m = blockIdx.x;
  int b = m >> 11;
  int tid = threadIdx.x;
  const float4* row = reinterpret_cast<const float4*>(x + (size_t)m * D_);
  float4 v = row[tid];
  float s = v.x + v.y + v.z + v.w;
  float ss = v.x * v.x + v.y * v.y + v.z * v.z + v.w * v.w;
#pragma unroll
  for (int o = 1; o < 64; o <<= 1) { s += __shfl_xor(s, o); ss += __shfl_xor(ss, o); }
  __shared__ float rs[4], rq[4];
  if ((tid & 63) == 0) { rs[tid >> 6] = s; rq[tid >> 6] = ss; }
  __syncthreads();
  s = rs[0] + rs[1] + rs[2] + rs[3];
  ss = rq[0] + rq[1] + rq[2] + rq[3];
  float mu = s * (1.f / D_);
  float rinv = rsqrtf(ss * (1.f / D_) - mu * mu + 1e-5f);
  int n = tid * 4;
  const float* mb = modset + b * 3072;
  float4 sh = *reinterpret_cast<const float4*>(mb + n);
  float4 sc = *reinterpret_cast<const float4*>(mb + 1024 + n);
  ushort4 o4;
  o4.x = f2bf((v.x - mu) * rinv * (1.f + sc.x) + sh.x);
  o4.y = f2bf((v.y - mu) * rinv * (1.f + sc.y) + sh.y);
  o4.z = f2bf((v.z - mu) * rinv * (1.f + sc.z) + sh.z);
  o4.w = f2bf((v.w - mu) * rinv * (1.f + sc.w) + sh.w);
  *reinterpret_cast<ushort4*>(out + (size_t)m * D_ + n) = o4;
}

// ---------------- RoPE in-place on bf16 q,k planes of qkv (M x 3072 bf16)
__global__ __launch_bounds__(256) void rope_bf(u16* __restrict__ qkv,
                                               const float* __restrict__ cs,
                                               const float* __restrict__ sn) {
  int idx = blockIdx.x * 256 + threadIdx.x;   // M*16*32
  int i = idx & 31;
  int hh = (idx >> 5) & 15;
  int mm = idx >> 9;
  int s = mm & (S_ - 1);
  float c = cs[s * 32 + i], si = sn[s * 32 + i];
  size_t base = (size_t)mm * 3072 + hh * 64 + 2 * i;
  unsigned* qp = reinterpret_cast<unsigned*>(qkv + base);
  unsigned* kp = reinterpret_cast<unsigned*>(qkv + base + 1024);
  unsigned qv = *qp, kv = *kp;
  float qx = bf2f((u16)(qv & 0xffff)), qy = bf2f((u16)(qv >> 16));
  float kx = bf2f((u16)(kv & 0xffff)), ky = bf2f((u16)(kv >> 16));
  *qp = (unsigned)f2bf(qx * c - qy * si) | ((unsigned)f2bf(qx * si + qy * c) << 16);
  *kp = (unsigned)f2bf(kx * c - ky * si) | ((unsigned)f2bf(kx * si + ky * c) << 16);
}

// ---------------- MFMA sliding-window flash attention
// block: 256 thr = 4 waves; wave w owns 16 queries (q0+16w..+15); KV chunks of 32
__global__ __launch_bounds__(256) void attn_mfma(const u16* __restrict__ qkv,
                                                 u16* __restrict__ out) {
  int q0 = blockIdx.x * 64;
  int h = blockIdx.y, b = blockIdx.z;
  __shared__ __align__(16) u16 Ks[2048];          // [32 j][64 d], 16B-granule XOR swizzle by j
  __shared__ __align__(16) u16 Vt[2048];          // [64 d][32 j], XOR swizzle by d
  __shared__ __align__(16) u16 Ps[4][16][40];     // per-wave P tile, padded
  int tid = threadIdx.x, lane = tid & 63, w = tid >> 6;
  int l4 = lane >> 4, lc = lane & 15;
  const u16* qrow = qkv + (size_t)(b * S_ + q0 + w * 16 + lc) * 3072 + h * 64;
  bf16x8 aq0 = *reinterpret_cast<const bf16x8*>(qrow + l4 * 8);
  bf16x8 aq1 = *reinterpret_cast<const bf16x8*>(qrow + 32 + l4 * 8);
  int qw0 = q0 + w * 16;
  float mrow[4], lsum[4];
  f32x4 oacc[4];
#pragma unroll
  for (int r = 0; r < 4; ++r) {
    mrow[r] = -__builtin_inff(); lsum[r] = 0.f;
    oacc[r] = f32x4{0.f, 0.f, 0.f, 0.f};
  }
  int kj = lane >> 3;            // 0..7 (+w*8)
  int kcb = (lane & 7) * 16;
  int vj = tid & 31;
  int vd0 = (tid >> 5) * 8;
  int jstart = q0 - WIN_; if (jstart < 0) jstart = 0;
  for (int jb = jstart; jb < q0 + 64; jb += 32) {
    __syncthreads();
    { // stage K chunk: wave w fills rows w*8..w*8+7, pre-swizzled global source
      int j = w * 8 + kj;
      const char* src = reinterpret_cast<const char*>(
          qkv + (size_t)(b * S_ + jb + j) * 3072 + 1024 + h * 64) + (kcb ^ ((j & 7) << 4));
      __builtin_amdgcn_global_load_lds((gptr_t)src,
          (lptr_t)(reinterpret_cast<char*>(Ks) + w * 1024), 16, 0, 0);
    }
    { // stage V transposed: thread reads V[j][d0..d0+8], writes Vt[d][2j ^ swz(d)]
      bf16x8 v = *reinterpret_cast<const bf16x8*>(
          qkv + (size_t)(b * S_ + jb + vj) * 3072 + 2048 + h * 64 + vd0);
#pragma unroll
      for (int k2 = 0; k2 < 8; ++k2) {
        int d = vd0 + k2;
        int cb = (2 * vj) ^ (((d >> 1) & 3) << 4);
        *reinterpret_cast<u16*>(reinterpret_cast<char*>(Vt) + d * 64 + cb) = (u16)v[k2];
      }
    }
    __syncthreads();
    if (jb + 31 >= qw0 - WIN_ && jb <= qw0 + 15) {
      f32x4 sacc[2] = {f32x4{0,0,0,0}, f32x4{0,0,0,0}};
#pragma unroll
      for (int jt = 0; jt < 2; ++jt) {
        int j = jt * 16 + lc;
#pragma unroll
        for (int kh = 0; kh < 2; ++kh) {
          int cbb = (kh * 64 + l4 * 16) ^ ((j & 7) << 4);
          bf16x8 bk = *reinterpret_cast<const bf16x8*>(
              reinterpret_cast<char*>(Ks) + j * 128 + cbb);
          sacc[jt] = __builtin_amdgcn_mfma_f32_16x16x32_bf16(kh == 0 ? aq0 : aq1, bk, sacc[jt], 0, 0, 0);
        }
      }
      float pv[2][4], rr[4];
#pragma unroll
      for (int r = 0; r < 4; ++r) {
        int qa = qw0 + l4 * 4 + r;
        float se[2];
        float cm = -__builtin_inff();
#pragma unroll
        for (int jt = 0; jt < 2; ++jt) {
          int ja = jb + jt * 16 + lc;
          bool val = (ja <= qa) && (qa - ja <= WIN_);
          se[jt] = val ? sacc[jt][r] * SCALE_ : -__builtin_inff();
          cm = fmaxf(cm, se[jt]);
        }
        cm = fmaxf(cm, __shfl_xor(cm, 1));
        cm = fmaxf(cm, __shfl_xor(cm, 2));
        cm = fmaxf(cm, __shfl_xor(cm, 4));
        cm = fmaxf(cm, __shfl_xor(cm, 8));
        float mnew = fmaxf(mrow[r], cm);
        float esum = 0.f;
#pragma unroll
        for (int jt = 0; jt < 2; ++jt) {
          float e = __expf(se[jt] - mnew);
          e = (se[jt] == -__builtin_inff()) ? 0.f : e;
          pv[jt][r] = e;
          esum += e;
        }
        esum += __shfl_xor(esum, 1);
        esum += __shfl_xor(esum, 2);
        esum += __shfl_xor(esum, 4);
        esum += __shfl_xor(esum, 8);
        float rf = __expf(mrow[r] - mnew);
        rf = (mnew == -__builtin_inff()) ? 0.f : rf;
        rr[r] = rf;
        lsum[r] = lsum[r] * rf + esum;
        mrow[r] = mnew;
      }
#pragma unroll
      for (int jt = 0; jt < 2; ++jt)
#pragma unroll
        for (int r = 0; r < 4; ++r)
          Ps[w][l4 * 4 + r][jt * 16 + lc] = f2bf(pv[jt][r]);
      asm volatile("s_waitcnt lgkmcnt(0)" ::: "memory");
      __builtin_amdgcn_sched_barrier(0);
      bf16x8 ap = *reinterpret_cast<const bf16x8*>(&Ps[w][lc][l4 * 8]);
#pragma unroll
      for (int dt = 0; dt < 4; ++dt) {
        int d = dt * 16 + lc;
        int cb = (l4 * 16) ^ (((d >> 1) & 3) << 4);
        bf16x8 bv = *reinterpret_cast<const bf16x8*>(
            reinterpret_cast<char*>(Vt) + d * 64 + cb);
#pragma unroll
        for (int r = 0; r < 4; ++r) oacc[dt][r] *= rr[r];
        oacc[dt] = __builtin_amdgcn_mfma_f32_16x16x32_bf16(ap, bv, oacc[dt], 0, 0, 0);
      }
    }
  }
  float inv[4];
#pragma unroll
  for (int r = 0; r < 4; ++r) inv[r] = 1.f / lsum[r];
  size_t obase = (size_t)(b * S_ + qw0) * D_ + h * 64;
#pragma unroll
  for (int dt = 0; dt < 4; ++dt)
#pragma unroll
    for (int r = 0; r < 4; ++r)
      out[obase + (size_t)(l4 * 4 + r) * D_ + dt * 16 + lc] = f2bf(oacc[dt][r] * inv[r]);
}

// ---------------- swiglu
__global__ __launch_bounds__(256) void swiglu_kernel(const u16* __restrict__ g,
                                                     u16* __restrict__ out) {
  int idx = blockIdx.x * 256 + threadIdx.x;   // M*1024 quads
  int m = idx >> 10, n4 = (idx & 1023) * 4;
  const u16* gr = g + (size_t)m * 8192;
  ushort4 a = *reinterpret_cast<const ushort4*>(gr + n4);
  ushort4 c = *reinterpret_cast<const ushort4*>(gr + 4096 + n4);
  ushort4 o;
  float af;
  af = bf2f(a.x); o.x = f2bf(af / (1.f + __expf(-af)) * bf2f(c.x));
  af = bf2f(a.y); o.y = f2bf(af / (1.f + __expf(-af)) * bf2f(c.y));
  af = bf2f(a.z); o.z = f2bf(af / (1.f + __expf(-af)) * bf2f(c.z));
  af = bf2f(a.w); o.w = f2bf(af / (1.f + __expf(-af)) * bf2f(c.w));
  *reinterpret_cast<ushort4*>(out + (size_t)m * 4096 + n4) = o;
}

// ---------------- bf16 MFMA GEMM:  C(MxN) = A(MxK) @ Bt(NxK)^T, 128x128 tile, BK=32
DEV bf16x8 read_frag(const u16* tile, int r16, int lane) {
  int r = r16 + (lane & 15);
  int cb = ((lane >> 4) << 4) ^ (((r >> 1) & 3) << 4);
  return *reinterpret_cast<const bf16x8*>(reinterpret_cast<const char*>(tile) + r * 64 + cb);
}

DEV void stage_tile(const u16* __restrict__ src, int ld, int rowBase, int kBase,
                    u16* tile, int tid) {
#pragma unroll
  for (int c = 0; c < 2; ++c) {
    int row = c * 64 + (tid >> 2);
    int cbs = ((tid & 3) << 4) ^ (((row >> 1) & 3) << 4);
    const char* g = reinterpret_cast<const char*>(src + (size_t)(rowBase + row) * ld + kBase) + cbs;
    char* l = reinterpret_cast<char*>(tile) + c * 4096 + (tid >> 6) * 1024;
    __builtin_amdgcn_global_load_lds((gptr_t)g, (lptr_t)l, 16, 0, 0);
  }
}

template <int EPI>
__global__ __launch_bounds__(256, 2) void gemm_bt(const u16* __restrict__ A,
                                                  const u16* __restrict__ Bt,
                                                  int M, int N, int K,
                                                  void* __restrict__ Cv,
                                                  const float* __restrict__ gate,
                                                  const float* __restrict__ resid) {
  __shared__ __align__(16) u16 lds[2][2][4096];
  int tid = threadIdx.x;
  int lane = tid & 63;
  int w = tid >> 6;
  int wr = w >> 1, wc = w & 1;
  int m0 = blockIdx.y * 128;
  int n0 = blockIdx.x * 128;
  f32x4 zero = {0.f, 0.f, 0.f, 0.f};
  f32x4 acc[4][4];
#pragma unroll
  for (int i = 0; i < 4; ++i)
#pragma unroll
    for (int j = 0; j < 4; ++j) acc[i][j] = zero;
  stage_tile(A, K, m0, 0, &lds[0][0][0], tid);
  stage_tile(Bt, K, n0, 0, &lds[0][1][0], tid);
  __syncthreads();
  int nt = K >> 5;
  int cur = 0;
  for (int t = 0; t < nt; ++t) {
    if (t + 1 < nt) {
      stage_tile(A, K, m0, (t + 1) << 5, &lds[cur ^ 1][0][0], tid);
      stage_tile(Bt, K, n0, (t + 1) << 5, &lds[cur ^ 1][1][0], tid);
    }
    bf16x8 af[4], bfr[4];
#pragma unroll
    for (int i = 0; i < 4; ++i) af[i] = read_frag(&lds[cur][0][0], wr * 64 + i * 16, lane);
#pragma unroll
    for (int i = 0; i < 4; ++i) bfr[i] = read_frag(&lds[cur][1][0], wc * 64 + i * 16, lane);
#pragma unroll
    for (int i = 0; i < 4; ++i)
#pragma unroll
      for (int j = 0; j < 4; ++j)
        acc[i][j] = __builtin_amdgcn_mfma_f32_16x16x32_bf16(af[i], bfr[j], acc[i][j], 0, 0, 0);
    __syncthreads();
    cur ^= 1;
  }
  int colB = n0 + wc * 64 + (lane & 15);
  int rowB = m0 + wr * 64 + ((lane >> 4) << 2);
#pragma unroll
  for (int i = 0; i < 4; ++i) {
#pragma unroll
    for (int j = 0; j < 4; ++j) {
      int col = colB + j * 16;
#pragma unroll
      for (int jr = 0; jr < 4; ++jr) {
        int row = rowB + i * 16 + jr;
        float v = acc[i][j][jr];
        size_t idx = (size_t)row * N + col;
        if constexpr (EPI == 0) {
          reinterpret_cast<float*>(Cv)[idx] = v;
        } else if constexpr (EPI == 1) {
          int bb = row >> 11;
          reinterpret_cast<float*>(Cv)[idx] = resid[idx] + gate[bb * 3072 + col] * v;
        } else {
          reinterpret_cast<u16*>(Cv)[idx] = f2bf(v);
        }
      }
    }
  }
}

extern "C" void kernel_launch(void* const* d_in, const int* in_sizes, int n_in,
                              void* d_out, int out_size, void* d_ws, size_t ws_size,
                              hipStream_t stream) {
  const float* x    = (const float*)d_in[0];
  const float* rc   = (const float*)d_in[1];
  const float* rs   = (const float*)d_in[2];
  const float* cond = (const float*)d_in[3];
  const float* wq   = (const float*)d_in[4];
  const float* wk   = (const float*)d_in[5];
  const float* wv   = (const float*)d_in[6];
  const float* wo   = (const float*)d_in[7];
  const float* aaw  = (const float*)d_in[8];
  const float* aab  = (const float*)d_in[9];
  const float* afw  = (const float*)d_in[10];
  const float* afb  = (const float*)d_in[11];
  const float* w1   = (const float*)d_in[12];
  const float* w3   = (const float*)d_in[13];
  const float* w2   = (const float*)d_in[14];
  float* out = (float*)d_out;
  char* ws = (char*)d_ws;

  u16*   wt_qkv = (u16*)  (ws + 0);           // 3072x1024 bf16
  u16*   wt_o   = (u16*)  (ws + 6291456);     // 1024x1024
  u16*   wt_13  = (u16*)  (ws + 8388608);     // 8192x1024
  u16*   wt_2   = (u16*)  (ws + 25165824);    // 1024x4096
  float* modf   = (float*)(ws + 33554432);    // [2 sets][B][3072]
  u16*   norm_b = (u16*)  (ws + 33603584);    // M x 1024 bf16
  u16*   attn_b = (u16*)  (ws + 41992192);    // M x 1024 bf16
  u16*   qkv_bf = (u16*)  (ws + 50380800);    // M x 3072 bf16
  u16*   g_bf   = (u16*)  (ws + 50380800);    // M x 8192 bf16 (aliases qkv: disjoint live range)
  float* hbuf   = (float*)(ws + 117489664);   // M x 1024 f32
  u16*   swig_b = (u16*)  (ws + 134266880);   // M x 4096 bf16

  adaln_mod<<<dim3(12, 2), 256, 0, stream>>>(cond, aaw, aab, modf);
  adaln_mod<<<dim3(12, 2), 256, 0, stream>>>(cond, afw, afb, modf + 6144);
  transpose_cast<<<dim3(32, 32), 256, 0, stream>>>(wq, 1024, 1024, wt_qkv);
  transpose_cast<<<dim3(32, 32), 256, 0, stream>>>(wk, 1024, 1024, wt_qkv + 1048576);
  transpose_cast<<<dim3(32, 32), 256, 0, stream>>>(wv, 1024, 1024, wt_qkv + 2097152);
  transpose_cast<<<dim3(32, 32), 256, 0, stream>>>(wo, 1024, 1024, wt_o);
  transpose_cast<<<dim3(128, 32), 256, 0, stream>>>(w1, 1024, 4096, wt_13);
  transpose_cast<<<dim3(128, 32), 256, 0, stream>>>(w3, 1024, 4096, wt_13 + 4194304);
  transpose_cast<<<dim3(32, 128), 256, 0, stream>>>(w2, 4096, 1024, wt_2);

  ln_mod_kernel<<<4096, 256, 0, stream>>>(x, modf, norm_b);
  gemm_bt<2><<<dim3(24, 32), 256, 0, stream>>>(norm_b, wt_qkv, M_, 3072, 1024, qkv_bf, nullptr, nullptr);
  rope_bf<<<8192, 256, 0, stream>>>(qkv_bf, rc, rs);
  attn_mfma<<<dim3(32, 16, 2), 256, 0, stream>>>(qkv_bf, attn_b);
  gemm_bt<1><<<dim3(8, 32), 256, 0, stream>>>(attn_b, wt_o, M_, 1024, 1024, hbuf, modf + 2048, x);
  ln_mod_kernel<<<4096, 256, 0, stream>>>(hbuf, modf + 6144, norm_b);
  gemm_bt<2><<<dim3(64, 32), 256, 0, stream>>>(norm_b, wt_13, M_, 8192, 1024, g_bf, nullptr, nullptr);
  swiglu_kernel<<<16384, 256, 0, stream>>>(g_bf, swig_b);
  gemm_bt<1><<<dim3(8, 32), 256, 0, stream>>>(swig_b, wt_2, M_, 1024, 4096, out, modf + 6144 + 2048, hbuf);
}

// Round 3
// 333.740 us; speedup vs baseline: 2.0949x; 1.5745x over previous
//
#include <hip/hip_runtime.h>

#define DEV __device__ __forceinline__

using bf16x8 = __attribute__((ext_vector_type(8))) short;
using f32x4  = __attribute__((ext_vector_type(4))) float;
using u16 = unsigned short;

constexpr int S_   = 2048;
constexpr int D_   = 1024;
constexpr int M_   = 4096;   // B*S tokens
constexpr int WIN_ = 256;
constexpr float SCALE_ = 0.125f;

typedef const __attribute__((address_space(1))) void* gptr_t;
typedef __attribute__((address_space(3))) void* lptr_t;

DEV u16 f2bf(float f) {
  unsigned u = __builtin_bit_cast(unsigned, f);
  return (u16)((u + 0x7fffu + ((u >> 16) & 1u)) >> 16);
}
DEV float bf2f(u16 b) {
  unsigned u = ((unsigned)b) << 16;
  return __builtin_bit_cast(float, u);
}

// ---------------- transpose + bf16 cast:  src (K x N) f32  ->  dst (N x K) bf16
__global__ __launch_bounds__(256) void transpose_cast(const float* __restrict__ src, int K, int N,
                                                      u16* __restrict__ dst) {
  __shared__ float tile[32][33];
  int n0 = blockIdx.x * 32, k0 = blockIdx.y * 32;
  int tx = threadIdx.x & 31, ty = threadIdx.x >> 5;   // ty 0..7
#pragma unroll
  for (int p = 0; p < 4; ++p)
    tile[ty + p * 8][tx] = src[(size_t)(k0 + ty + p * 8) * N + n0 + tx];
  __syncthreads();
#pragma unroll
  for (int p = 0; p < 4; ++p)
    dst[(size_t)(n0 + ty + p * 8) * K + k0 + tx] = f2bf(tile[tx][ty + p * 8]);
}

// ---------------- adaLN modulation: split-K partials  part[sb][ks][3072]
__global__ __launch_bounds__(256) void adaln_part(const float* __restrict__ cond,
                                                  const float* __restrict__ Wa,
                                                  const float* __restrict__ Wf,
                                                  float* __restrict__ part) {
  int n = blockIdx.x * 256 + threadIdx.x;
  int ks = blockIdx.y;           // 0..7 (128 c-rows each)
  int sb = blockIdx.z;           // set*2 + b
  int b = sb & 1;
  const float* W = (sb & 2) ? Wf : Wa;
  __shared__ float sc[128];
  if (threadIdx.x < 128) {
    float c = cond[b * 1024 + ks * 128 + threadIdx.x];
    sc[threadIdx.x] = c / (1.f + __expf(-c));
  }
  __syncthreads();
  float acc = 0.f;
  const float* Wp = W + (size_t)(ks * 128) * 3072 + n;
#pragma unroll 4
  for (int c = 0; c < 128; ++c) acc += sc[c] * Wp[(size_t)c * 3072];
  part[(size_t)(sb * 8 + ks) * 3072 + n] = acc;
}

__global__ __launch_bounds__(256) void adaln_reduce(const float* __restrict__ part,
                                                    const float* __restrict__ ba,
                                                    const float* __restrict__ bfb,
                                                    float* __restrict__ modout) {
  int n = blockIdx.x * 256 + threadIdx.x;
  int sb = blockIdx.y;           // set*2 + b
  float acc = ((sb & 2) ? bfb : ba)[n];
#pragma unroll
  for (int k = 0; k < 8; ++k) acc += part[(size_t)(sb * 8 + k) * 3072 + n];
  modout[sb * 3072 + n] = acc;   // layout [set][b][3072]
}

// ---------------- LayerNorm + (1+scale)*x + shift -> bf16
__global__ __launch_bounds__(256) void ln_mod_kernel(const float* __restrict__ x,
                                                     const float* __restrict__ modset,
                                                     u16* __restrict__ out) {
  int m = blockIdx.x;
  int b = m >> 11;
  int tid = threadIdx.x;
  const float4* row = reinterpret_cast<const float4*>(x + (size_t)m * D_);
  float4 v = row[tid];
  float s = v.x + v.y + v.z + v.w;
  float ss = v.x * v.x + v.y * v.y + v.z * v.z + v.w * v.w;
#pragma unroll
  for (int o = 1; o < 64; o <<= 1) { s += __shfl_xor(s, o); ss += __shfl_xor(ss, o); }
  __shared__ float rs[4], rq[4];
  if ((tid & 63) == 0) { rs[tid >> 6] = s; rq[tid >> 6] = ss; }
  __syncthreads();
  s = rs[0] + rs[1] + rs[2] + rs[3];
  ss = rq[0] + rq[1] + rq[2] + rq[3];
  float mu = s * (1.f / D_);
  float rinv = rsqrtf(ss * (1.f / D_) - mu * mu + 1e-5f);
  int n = tid * 4;
  const float* mb = modset + b * 3072;
  float4 sh = *reinterpret_cast<const float4*>(mb + n);
  float4 sc = *reinterpret_cast<const float4*>(mb + 1024 + n);
  ushort4 o4;
  o4.x = f2bf((v.x - mu) * rinv * (1.f + sc.x) + sh.x);
  o4.y = f2bf((v.y - mu) * rinv * (1.f + sc.y) + sh.y);
  o4.z = f2bf((v.z - mu) * rinv * (1.f + sc.z) + sh.z);
  o4.w = f2bf((v.w - mu) * rinv * (1.f + sc.w) + sh.w);
  *reinterpret_cast<ushort4*>(out + (size_t)m * D_ + n) = o4;
}

// ---------------- RoPE in-place on bf16 q,k planes of qkv (M x 3072 bf16)
__global__ __launch_bounds__(256) void rope_bf(u16* __restrict__ qkv,
                                               const float* __restrict__ cs,
                                               const float* __restrict__ sn) {
  int idx = blockIdx.x * 256 + threadIdx.x;   // M*16*32
  int i = idx & 31;
  int hh = (idx >> 5) & 15;
  int mm = idx >> 9;
  int s = mm & (S_ - 1);
  float c = cs[s * 32 + i], si = sn[s * 32 + i];
  size_t base = (size_t)mm * 3072 + hh * 64 + 2 * i;
  unsigned* qp = reinterpret_cast<unsigned*>(qkv + base);
  unsigned* kp = reinterpret_cast<unsigned*>(qkv + base + 1024);
  unsigned qv = *qp, kv = *kp;
  float qx = bf2f((u16)(qv & 0xffff)), qy = bf2f((u16)(qv >> 16));
  float kx = bf2f((u16)(kv & 0xffff)), ky = bf2f((u16)(kv >> 16));
  *qp = (unsigned)f2bf(qx * c - qy * si) | ((unsigned)f2bf(qx * si + qy * c) << 16);
  *kp = (unsigned)f2bf(kx * c - ky * si) | ((unsigned)f2bf(kx * si + ky * c) << 16);
}

// ---------------- MFMA sliding-window flash attention
__global__ __launch_bounds__(256) void attn_mfma(const u16* __restrict__ qkv,
                                                 u16* __restrict__ out) {
  int q0 = blockIdx.x * 64;
  int h = blockIdx.y, b = blockIdx.z;
  __shared__ __align__(16) u16 Ks[2048];          // [32 j][64 d], 16B-granule XOR swizzle by j
  __shared__ __align__(16) u16 Vt[2048];          // [64 d][32 j], XOR swizzle by d
  __shared__ __align__(16) u16 Ps[4][16][40];     // per-wave P tile, padded
  int tid = threadIdx.x, lane = tid & 63, w = tid >> 6;
  int l4 = lane >> 4, lc = lane & 15;
  const u16* qrow = qkv + (size_t)(b * S_ + q0 + w * 16 + lc) * 3072 + h * 64;
  bf16x8 aq0 = *reinterpret_cast<const bf16x8*>(qrow + l4 * 8);
  bf16x8 aq1 = *reinterpret_cast<const bf16x8*>(qrow + 32 + l4 * 8);
  int qw0 = q0 + w * 16;
  float mrow[4], lsum[4];
  f32x4 oacc[4];
#pragma unroll
  for (int r = 0; r < 4; ++r) {
    mrow[r] = -__builtin_inff(); lsum[r] = 0.f;
    oacc[r] = f32x4{0.f, 0.f, 0.f, 0.f};
  }
  int kj = lane >> 3;            // 0..7 (+w*8)
  int kcb = (lane & 7) * 16;
  int vj = tid & 31;
  int vd0 = (tid >> 5) * 8;
  int jstart = q0 - WIN_; if (jstart < 0) jstart = 0;
  for (int jb = jstart; jb < q0 + 64; jb += 32) {
    __syncthreads();
    { // stage K chunk: wave w fills rows w*8..w*8+7, pre-swizzled global source
      int j = w * 8 + kj;
      const char* src = reinterpret_cast<const char*>(
          qkv + (size_t)(b * S_ + jb + j) * 3072 + 1024 + h * 64) + (kcb ^ ((j & 7) << 4));
      __builtin_amdgcn_global_load_lds((gptr_t)src,
          (lptr_t)(reinterpret_cast<char*>(Ks) + w * 1024), 16, 0, 0);
    }
    { // stage V transposed: thread reads V[j][d0..d0+8], writes Vt[d][2j ^ swz(d)]
      bf16x8 v = *reinterpret_cast<const bf16x8*>(
          qkv + (size_t)(b * S_ + jb + vj) * 3072 + 2048 + h * 64 + vd0);
#pragma unroll
      for (int k2 = 0; k2 < 8; ++k2) {
        int d = vd0 + k2;
        int cb = (2 * vj) ^ (((d >> 1) & 3) << 4);
        *reinterpret_cast<u16*>(reinterpret_cast<char*>(Vt) + d * 64 + cb) = (u16)v[k2];
      }
    }
    __syncthreads();
    if (jb + 31 >= qw0 - WIN_ && jb <= qw0 + 15) {
      f32x4 sacc[2] = {f32x4{0,0,0,0}, f32x4{0,0,0,0}};
#pragma unroll
      for (int jt = 0; jt < 2; ++jt) {
        int j = jt * 16 + lc;
#pragma unroll
        for (int kh = 0; kh < 2; ++kh) {
          int cbb = (kh * 64 + l4 * 16) ^ ((j & 7) << 4);
          bf16x8 bk = *reinterpret_cast<const bf16x8*>(
              reinterpret_cast<char*>(Ks) + j * 128 + cbb);
          sacc[jt] = __builtin_amdgcn_mfma_f32_16x16x32_bf16(kh == 0 ? aq0 : aq1, bk, sacc[jt], 0, 0, 0);
        }
      }
      float pv[2][4], rr[4];
#pragma unroll
      for (int r = 0; r < 4; ++r) {
        int qa = qw0 + l4 * 4 + r;
        float se[2];
        float cm = -__builtin_inff();
#pragma unroll
        for (int jt = 0; jt < 2; ++jt) {
          int ja = jb + jt * 16 + lc;
          bool val = (ja <= qa) && (qa - ja <= WIN_);
          se[jt] = val ? sacc[jt][r] * SCALE_ : -__builtin_inff();
          cm = fmaxf(cm, se[jt]);
        }
        cm = fmaxf(cm, __shfl_xor(cm, 1));
        cm = fmaxf(cm, __shfl_xor(cm, 2));
        cm = fmaxf(cm, __shfl_xor(cm, 4));
        cm = fmaxf(cm, __shfl_xor(cm, 8));
        float mnew = fmaxf(mrow[r], cm);
        float esum = 0.f;
#pragma unroll
        for (int jt = 0; jt < 2; ++jt) {
          float e = __expf(se[jt] - mnew);
          e = (se[jt] == -__builtin_inff()) ? 0.f : e;
          pv[jt][r] = e;
          esum += e;
        }
        esum += __shfl_xor(esum, 1);
        esum += __shfl_xor(esum, 2);
        esum += __shfl_xor(esum, 4);
        esum += __shfl_xor(esum, 8);
        float rf = __expf(mrow[r] - mnew);
        rf = (mnew == -__builtin_inff()) ? 0.f : rf;
        rr[r] = rf;
        lsum[r] = lsum[r] * rf + esum;
        mrow[r] = mnew;
      }
#pragma unroll
      for (int jt = 0; jt < 2; ++jt)
#pragma unroll
        for (int r = 0; r < 4; ++r)
          Ps[w][l4 * 4 + r][jt * 16 + lc] = f2bf(pv[jt][r]);
      asm volatile("s_waitcnt lgkmcnt(0)" ::: "memory");
      __builtin_amdgcn_sched_barrier(0);
      bf16x8 ap = *reinterpret_cast<const bf16x8*>(&Ps[w][lc][l4 * 8]);
#pragma unroll
      for (int dt = 0; dt < 4; ++dt) {
        int d = dt * 16 + lc;
        int cb = (l4 * 16) ^ (((d >> 1) & 3) << 4);
        bf16x8 bv = *reinterpret_cast<const bf16x8*>(
            reinterpret_cast<char*>(Vt) + d * 64 + cb);
#pragma unroll
        for (int r = 0; r < 4; ++r) oacc[dt][r] *= rr[r];
        oacc[dt] = __builtin_amdgcn_mfma_f32_16x16x32_bf16(ap, bv, oacc[dt], 0, 0, 0);
      }
    }
  }
  float inv[4];
#pragma unroll
  for (int r = 0; r < 4; ++r) inv[r] = 1.f / lsum[r];
  size_t obase = (size_t)(b * S_ + qw0) * D_ + h * 64;
#pragma unroll
  for (int dt = 0; dt < 4; ++dt)
#pragma unroll
    for (int r = 0; r < 4; ++r)
      out[obase + (size_t)(l4 * 4 + r) * D_ + dt * 16 + lc] = f2bf(oacc[dt][r] * inv[r]);
}

// ---------------- swiglu
__global__ __launch_bounds__(256) void swiglu_kernel(const u16* __restrict__ g,
                                                     u16* __restrict__ out) {
  int idx = blockIdx.x * 256 + threadIdx.x;   // M*1024 quads
  int m = idx >> 10, n4 = (idx & 1023) * 4;
  const u16* gr = g + (size_t)m * 8192;
  ushort4 a = *reinterpret_cast<const ushort4*>(gr + n4);
  ushort4 c = *reinterpret_cast<const ushort4*>(gr + 4096 + n4);
  ushort4 o;
  float af;
  af = bf2f(a.x); o.x = f2bf(af / (1.f + __expf(-af)) * bf2f(c.x));
  af = bf2f(a.y); o.y = f2bf(af / (1.f + __expf(-af)) * bf2f(c.y));
  af = bf2f(a.z); o.z = f2bf(af / (1.f + __expf(-af)) * bf2f(c.z));
  af = bf2f(a.w); o.w = f2bf(af / (1.f + __expf(-af)) * bf2f(c.w));
  *reinterpret_cast<ushort4*>(out + (size_t)m * 4096 + n4) = o;
}

// ---------------- bf16 MFMA GEMM:  C(MxN) = A(MxK) @ Bt(NxK)^T, 128x128 tile, BK=32
DEV bf16x8 read_frag(const u16* tile, int r16, int lane) {
  int r = r16 + (lane & 15);
  int cb = ((lane >> 4) << 4) ^ (((r >> 1) & 3) << 4);
  return *reinterpret_cast<const bf16x8*>(reinterpret_cast<const char*>(tile) + r * 64 + cb);
}

DEV void stage_tile(const u16* __restrict__ src, int ld, int rowBase, int kBase,
                    u16* tile, int tid) {
#pragma unroll
  for (int c = 0; c < 2; ++c) {
    int row = c * 64 + (tid >> 2);
    int cbs = ((tid & 3) << 4) ^ (((row >> 1) & 3) << 4);
    const char* g = reinterpret_cast<const char*>(src + (size_t)(rowBase + row) * ld + kBase) + cbs;
    char* l = reinterpret_cast<char*>(tile) + c * 4096 + (tid >> 6) * 1024;
    __builtin_amdgcn_global_load_lds((gptr_t)g, (lptr_t)l, 16, 0, 0);
  }
}

template <int EPI>
__global__ __launch_bounds__(256, 2) void gemm_bt(const u16* __restrict__ A,
                                                  const u16* __restrict__ Bt,
                                                  int M, int N, int K,
                                                  void* __restrict__ Cv,
                                                  const float* __restrict__ gate,
                                                  const float* __restrict__ resid) {
  __shared__ __align__(16) u16 lds[2][2][4096];
  int tid = threadIdx.x;
  int lane = tid & 63;
  int w = tid >> 6;
  int wr = w >> 1, wc = w & 1;
  int m0 = blockIdx.y * 128;
  int n0 = blockIdx.x * 128;
  f32x4 zero = {0.f, 0.f, 0.f, 0.f};
  f32x4 acc[4][4];
#pragma unroll
  for (int i = 0; i < 4; ++i)
#pragma unroll
    for (int j = 0; j < 4; ++j) acc[i][j] = zero;
  stage_tile(A, K, m0, 0, &lds[0][0][0], tid);
  stage_tile(Bt, K, n0, 0, &lds[0][1][0], tid);
  __syncthreads();
  int nt = K >> 5;
  int cur = 0;
  for (int t = 0; t < nt; ++t) {
    if (t + 1 < nt) {
      stage_tile(A, K, m0, (t + 1) << 5, &lds[cur ^ 1][0][0], tid);
      stage_tile(Bt, K, n0, (t + 1) << 5, &lds[cur ^ 1][1][0], tid);
    }
    bf16x8 af[4], bfr[4];
#pragma unroll
    for (int i = 0; i < 4; ++i) af[i] = read_frag(&lds[cur][0][0], wr * 64 + i * 16, lane);
#pragma unroll
    for (int i = 0; i < 4; ++i) bfr[i] = read_frag(&lds[cur][1][0], wc * 64 + i * 16, lane);
#pragma unroll
    for (int i = 0; i < 4; ++i)
#pragma unroll
      for (int j = 0; j < 4; ++j)
        acc[i][j] = __builtin_amdgcn_mfma_f32_16x16x32_bf16(af[i], bfr[j], acc[i][j], 0, 0, 0);
    __syncthreads();
    cur ^= 1;
  }
  int colB = n0 + wc * 64 + (lane & 15);
  int rowB = m0 + wr * 64 + ((lane >> 4) << 2);
#pragma unroll
  for (int i = 0; i < 4; ++i) {
#pragma unroll
    for (int j = 0; j < 4; ++j) {
      int col = colB + j * 16;
#pragma unroll
      for (int jr = 0; jr < 4; ++jr) {
        int row = rowB + i * 16 + jr;
        float v = acc[i][j][jr];
        size_t idx = (size_t)row * N + col;
        if constexpr (EPI == 0) {
          reinterpret_cast<float*>(Cv)[idx] = v;
        } else if constexpr (EPI == 1) {
          int bb = row >> 11;
          reinterpret_cast<float*>(Cv)[idx] = resid[idx] + gate[bb * 3072 + col] * v;
        } else {
          reinterpret_cast<u16*>(Cv)[idx] = f2bf(v);
        }
      }
    }
  }
}

extern "C" void kernel_launch(void* const* d_in, const int* in_sizes, int n_in,
                              void* d_out, int out_size, void* d_ws, size_t ws_size,
                              hipStream_t stream) {
  const float* x    = (const float*)d_in[0];
  const float* rc   = (const float*)d_in[1];
  const float* rs   = (const float*)d_in[2];
  const float* cond = (const float*)d_in[3];
  const float* wq   = (const float*)d_in[4];
  const float* wk   = (const float*)d_in[5];
  const float* wv   = (const float*)d_in[6];
  const float* wo   = (const float*)d_in[7];
  const float* aaw  = (const float*)d_in[8];
  const float* aab  = (const float*)d_in[9];
  const float* afw  = (const float*)d_in[10];
  const float* afb  = (const float*)d_in[11];
  const float* w1   = (const float*)d_in[12];
  const float* w3   = (const float*)d_in[13];
  const float* w2   = (const float*)d_in[14];
  float* out = (float*)d_out;
  char* ws = (char*)d_ws;

  u16*   wt_qkv = (u16*)  (ws + 0);           // 3072x1024 bf16
  u16*   wt_o   = (u16*)  (ws + 6291456);     // 1024x1024
  u16*   wt_13  = (u16*)  (ws + 8388608);     // 8192x1024
  u16*   wt_2   = (u16*)  (ws + 25165824);    // 1024x4096
  float* modf   = (float*)(ws + 33554432);    // [2 sets][B][3072]
  u16*   norm_b = (u16*)  (ws + 33603584);    // M x 1024 bf16
  u16*   attn_b = (u16*)  (ws + 41992192);    // M x 1024 bf16
  u16*   qkv_bf = (u16*)  (ws + 50380800);    // M x 3072 bf16
  float* adpart = (float*)(ws + 50380800);    // [4 sb][8 ks][3072] f32 — dead before qkv GEMM
  u16*   g_bf   = (u16*)  (ws + 50380800);    // M x 8192 bf16 (aliases qkv: disjoint live range)
  float* hbuf   = (float*)(ws + 117489664);   // M x 1024 f32
  u16*   swig_b = (u16*)  (ws + 134266880);   // M x 4096 bf16

  adaln_part<<<dim3(12, 8, 4), 256, 0, stream>>>(cond, aaw, afw, adpart);
  adaln_reduce<<<dim3(12, 4), 256, 0, stream>>>(adpart, aab, afb, modf);
  transpose_cast<<<dim3(32, 32), 256, 0, stream>>>(wq, 1024, 1024, wt_qkv);
  transpose_cast<<<dim3(32, 32), 256, 0, stream>>>(wk, 1024, 1024, wt_qkv + 1048576);
  transpose_cast<<<dim3(32, 32), 256, 0, stream>>>(wv, 1024, 1024, wt_qkv + 2097152);
  transpose_cast<<<dim3(32, 32), 256, 0, stream>>>(wo, 1024, 1024, wt_o);
  transpose_cast<<<dim3(128, 32), 256, 0, stream>>>(w1, 1024, 4096, wt_13);
  transpose_cast<<<dim3(128, 32), 256, 0, stream>>>(w3, 1024, 4096, wt_13 + 4194304);
  transpose_cast<<<dim3(32, 128), 256, 0, stream>>>(w2, 4096, 1024, wt_2);

  ln_mod_kernel<<<4096, 256, 0, stream>>>(x, modf, norm_b);
  gemm_bt<2><<<dim3(24, 32), 256, 0, stream>>>(norm_b, wt_qkv, M_, 3072, 1024, qkv_bf, nullptr, nullptr);
  rope_bf<<<8192, 256, 0, stream>>>(qkv_bf, rc, rs);
  attn_mfma<<<dim3(32, 16, 2), 256, 0, stream>>>(qkv_bf, attn_b);
  gemm_bt<1><<<dim3(8, 32), 256, 0, stream>>>(attn_b, wt_o, M_, 1024, 1024, hbuf, modf + 2048, x);
  ln_mod_kernel<<<4096, 256, 0, stream>>>(hbuf, modf + 6144, norm_b);
  gemm_bt<2><<<dim3(64, 32), 256, 0, stream>>>(norm_b, wt_13, M_, 8192, 1024, g_bf, nullptr, nullptr);
  swiglu_kernel<<<16384, 256, 0, stream>>>(g_bf, swig_b);
  gemm_bt<1><<<dim3(8, 32), 256, 0, stream>>>(swig_b, wt_2, M_, 1024, 4096, out, modf + 6144 + 2048, hbuf);
}

// Round 4
// 319.264 us; speedup vs baseline: 2.1898x; 1.0453x over previous
//
#include <hip/hip_runtime.h>

#define DEV __device__ __forceinline__

using bf16x8 = __attribute__((ext_vector_type(8))) short;
using f32x4  = __attribute__((ext_vector_type(4))) float;
using u16 = unsigned short;

constexpr int S_   = 2048;
constexpr int D_   = 1024;
constexpr int M_   = 4096;   // B*S tokens
constexpr int WIN_ = 256;
constexpr float SCALE_ = 0.125f;

typedef const __attribute__((address_space(1))) void* gptr_t;
typedef __attribute__((address_space(3))) void* lptr_t;

DEV u16 f2bf(float f) {
  unsigned u = __builtin_bit_cast(unsigned, f);
  return (u16)((u + 0x7fffu + ((u >> 16) & 1u)) >> 16);
}
DEV float bf2f(u16 b) {
  unsigned u = ((unsigned)b) << 16;
  return __builtin_bit_cast(float, u);
}

// ---------------- transpose + bf16 cast: 4 square 1024x1024 weights in one launch
__global__ __launch_bounds__(256) void transpose_sq4(const float* __restrict__ s0,
                                                     const float* __restrict__ s1,
                                                     const float* __restrict__ s2,
                                                     const float* __restrict__ s3,
                                                     u16* d0, u16* d1, u16* d2, u16* d3) {
  const float* src; u16* dst;
  switch (blockIdx.z) {
    case 0: src = s0; dst = d0; break;
    case 1: src = s1; dst = d1; break;
    case 2: src = s2; dst = d2; break;
    default: src = s3; dst = d3;
  }
  __shared__ float tile[32][33];
  int n0 = blockIdx.x * 32, k0 = blockIdx.y * 32;
  int tx = threadIdx.x & 31, ty = threadIdx.x >> 5;
#pragma unroll
  for (int p = 0; p < 4; ++p)
    tile[ty + p * 8][tx] = src[(size_t)(k0 + ty + p * 8) * 1024 + n0 + tx];
  __syncthreads();
#pragma unroll
  for (int p = 0; p < 4; ++p)
    dst[(size_t)(n0 + ty + p * 8) * 1024 + k0 + tx] = f2bf(tile[tx][ty + p * 8]);
}

// ---------------- w1/w3 transpose with 16-col interleave: w1 col n -> row ((n>>4)<<5)+(n&15),
// w3 col n -> +16.  dst is 8192 x 1024 bf16.
__global__ __launch_bounds__(256) void transpose_13(const float* __restrict__ w1,
                                                    const float* __restrict__ w3,
                                                    u16* __restrict__ dst) {
  const float* src = blockIdx.z ? w3 : w1;
  int add = blockIdx.z ? 16 : 0;
  __shared__ float tile[32][33];
  int n0 = blockIdx.x * 32, k0 = blockIdx.y * 32;
  int tx = threadIdx.x & 31, ty = threadIdx.x >> 5;
#pragma unroll
  for (int p = 0; p < 4; ++p)
    tile[ty + p * 8][tx] = src[(size_t)(k0 + ty + p * 8) * 4096 + n0 + tx];
  __syncthreads();
#pragma unroll
  for (int p = 0; p < 4; ++p) {
    int n = n0 + ty + p * 8;
    int r = ((n >> 4) << 5) + add + (n & 15);
    dst[(size_t)r * 1024 + k0 + tx] = f2bf(tile[tx][ty + p * 8]);
  }
}

// ---------------- plain transpose (w2: 4096 x 1024 -> 1024 x 4096)
__global__ __launch_bounds__(256) void transpose_cast(const float* __restrict__ src, int K, int N,
                                                      u16* __restrict__ dst) {
  __shared__ float tile[32][33];
  int n0 = blockIdx.x * 32, k0 = blockIdx.y * 32;
  int tx = threadIdx.x & 31, ty = threadIdx.x >> 5;
#pragma unroll
  for (int p = 0; p < 4; ++p)
    tile[ty + p * 8][tx] = src[(size_t)(k0 + ty + p * 8) * N + n0 + tx];
  __syncthreads();
#pragma unroll
  for (int p = 0; p < 4; ++p)
    dst[(size_t)(n0 + ty + p * 8) * K + k0 + tx] = f2bf(tile[tx][ty + p * 8]);
}

// ---------------- adaLN modulation: split-K partials  part[sb][ks][3072]
__global__ __launch_bounds__(256) void adaln_part(const float* __restrict__ cond,
                                                  const float* __restrict__ Wa,
                                                  const float* __restrict__ Wf,
                                                  float* __restrict__ part) {
  int n = blockIdx.x * 256 + threadIdx.x;
  int ks = blockIdx.y;
  int sb = blockIdx.z;
  int b = sb & 1;
  const float* W = (sb & 2) ? Wf : Wa;
  __shared__ float sc[128];
  if (threadIdx.x < 128) {
    float c = cond[b * 1024 + ks * 128 + threadIdx.x];
    sc[threadIdx.x] = c / (1.f + __expf(-c));
  }
  __syncthreads();
  float acc = 0.f;
  const float* Wp = W + (size_t)(ks * 128) * 3072 + n;
#pragma unroll 4
  for (int c = 0; c < 128; ++c) acc += sc[c] * Wp[(size_t)c * 3072];
  part[(size_t)(sb * 8 + ks) * 3072 + n] = acc;
}

__global__ __launch_bounds__(256) void adaln_reduce(const float* __restrict__ part,
                                                    const float* __restrict__ ba,
                                                    const float* __restrict__ bfb,
                                                    float* __restrict__ modout) {
  int n = blockIdx.x * 256 + threadIdx.x;
  int sb = blockIdx.y;
  float acc = ((sb & 2) ? bfb : ba)[n];
#pragma unroll
  for (int k = 0; k < 8; ++k) acc += part[(size_t)(sb * 8 + k) * 3072 + n];
  modout[sb * 3072 + n] = acc;
}

// ---------------- LayerNorm + (1+scale)*x + shift -> bf16
__global__ __launch_bounds__(256) void ln_mod_kernel(const float* __restrict__ x,
                                                     const float* __restrict__ modset,
                                                     u16* __restrict__ out) {
  int m = blockIdx.x;
  int b = m >> 11;
  int tid = threadIdx.x;
  const float4* row = reinterpret_cast<const float4*>(x + (size_t)m * D_);
  float4 v = row[tid];
  float s = v.x + v.y + v.z + v.w;
  float ss = v.x * v.x + v.y * v.y + v.z * v.z + v.w * v.w;
#pragma unroll
  for (int o = 1; o < 64; o <<= 1) { s += __shfl_xor(s, o); ss += __shfl_xor(ss, o); }
  __shared__ float rs[4], rq[4];
  if ((tid & 63) == 0) { rs[tid >> 6] = s; rq[tid >> 6] = ss; }
  __syncthreads();
  s = rs[0] + rs[1] + rs[2] + rs[3];
  ss = rq[0] + rq[1] + rq[2] + rq[3];
  float mu = s * (1.f / D_);
  float rinv = rsqrtf(ss * (1.f / D_) - mu * mu + 1e-5f);
  int n = tid * 4;
  const float* mb = modset + b * 3072;
  float4 sh = *reinterpret_cast<const float4*>(mb + n);
  float4 sc = *reinterpret_cast<const float4*>(mb + 1024 + n);
  ushort4 o4;
  o4.x = f2bf((v.x - mu) * rinv * (1.f + sc.x) + sh.x);
  o4.y = f2bf((v.y - mu) * rinv * (1.f + sc.y) + sh.y);
  o4.z = f2bf((v.z - mu) * rinv * (1.f + sc.z) + sh.z);
  o4.w = f2bf((v.w - mu) * rinv * (1.f + sc.w) + sh.w);
  *reinterpret_cast<ushort4*>(out + (size_t)m * D_ + n) = o4;
}

// ---------------- rotate 4 (even,odd) bf16 pairs; freq idx base..base+3, seq pos s
DEV bf16x8 rope8(bf16x8 v, const float* __restrict__ cs, const float* __restrict__ sn,
                 int s, int base) {
  bf16x8 r;
#pragma unroll
  for (int t = 0; t < 4; ++t) {
    float c = cs[s * 32 + base + t], si = sn[s * 32 + base + t];
    float x = bf2f((u16)v[2 * t]), y = bf2f((u16)v[2 * t + 1]);
    r[2 * t] = (short)f2bf(x * c - y * si);
    r[2 * t + 1] = (short)f2bf(x * si + y * c);
  }
  return r;
}

// ---------------- MFMA sliding-window flash attention with fused RoPE
__global__ __launch_bounds__(256) void attn_mfma(const u16* __restrict__ qkv,
                                                 const float* __restrict__ cs,
                                                 const float* __restrict__ sn,
                                                 u16* __restrict__ out) {
  int q0 = blockIdx.x * 64;
  int h = blockIdx.y, b = blockIdx.z;
  __shared__ __align__(16) u16 Ks[2048];          // [32 j][64 d], 16B-granule XOR swizzle by j
  __shared__ __align__(16) u16 Vt[2048];          // [64 d][32 j], XOR swizzle by d
  __shared__ __align__(16) u16 Ps[4][16][40];     // per-wave P tile, padded
  int tid = threadIdx.x, lane = tid & 63, w = tid >> 6;
  int l4 = lane >> 4, lc = lane & 15;
  int sq = q0 + w * 16 + lc;                       // this lane's query seq pos
  const u16* qrow = qkv + (size_t)(b * S_ + sq) * 3072 + h * 64;
  bf16x8 aq0 = rope8(*reinterpret_cast<const bf16x8*>(qrow + l4 * 8), cs, sn, sq, l4 * 4);
  bf16x8 aq1 = rope8(*reinterpret_cast<const bf16x8*>(qrow + 32 + l4 * 8), cs, sn, sq, 16 + l4 * 4);
  int qw0 = q0 + w * 16;
  float mrow[4], lsum[4];
  f32x4 oacc[4];
#pragma unroll
  for (int r = 0; r < 4; ++r) {
    mrow[r] = -__builtin_inff(); lsum[r] = 0.f;
    oacc[r] = f32x4{0.f, 0.f, 0.f, 0.f};
  }
  int kj = lane >> 3;
  int kcb = (lane & 7) * 16;
  int vj = tid & 31;
  int vd0 = (tid >> 5) * 8;
  int jstart = q0 - WIN_; if (jstart < 0) jstart = 0;
  for (int jb = jstart; jb < q0 + 64; jb += 32) {
    __syncthreads();
    { // stage K chunk (un-roped): wave w fills rows w*8..w*8+7, pre-swizzled global source
      int j = w * 8 + kj;
      const char* src = reinterpret_cast<const char*>(
          qkv + (size_t)(b * S_ + jb + j) * 3072 + 1024 + h * 64) + (kcb ^ ((j & 7) << 4));
      __builtin_amdgcn_global_load_lds((gptr_t)src,
          (lptr_t)(reinterpret_cast<char*>(Ks) + w * 1024), 16, 0, 0);
    }
    { // stage V transposed
      bf16x8 v = *reinterpret_cast<const bf16x8*>(
          qkv + (size_t)(b * S_ + jb + vj) * 3072 + 2048 + h * 64 + vd0);
#pragma unroll
      for (int k2 = 0; k2 < 8; ++k2) {
        int d = vd0 + k2;
        int cb = (2 * vj) ^ (((d >> 1) & 3) << 4);
        *reinterpret_cast<u16*>(reinterpret_cast<char*>(Vt) + d * 64 + cb) = (u16)v[k2];
      }
    }
    __syncthreads();
    if (jb + 31 >= qw0 - WIN_ && jb <= qw0 + 15) {
      f32x4 sacc[2] = {f32x4{0,0,0,0}, f32x4{0,0,0,0}};
#pragma unroll
      for (int jt = 0; jt < 2; ++jt) {
        int j = jt * 16 + lc;
        int sk = jb + j;
#pragma unroll
        for (int kh = 0; kh < 2; ++kh) {
          int cbb = (kh * 64 + l4 * 16) ^ ((j & 7) << 4);
          bf16x8 bk = *reinterpret_cast<const bf16x8*>(
              reinterpret_cast<char*>(Ks) + j * 128 + cbb);
          bk = rope8(bk, cs, sn, sk, kh * 16 + l4 * 4);   // fused K-RoPE
          sacc[jt] = __builtin_amdgcn_mfma_f32_16x16x32_bf16(kh == 0 ? aq0 : aq1, bk, sacc[jt], 0, 0, 0);
        }
      }
      float pv[2][4], rr[4];
#pragma unroll
      for (int r = 0; r < 4; ++r) {
        int qa = qw0 + l4 * 4 + r;
        float se[2];
        float cm = -__builtin_inff();
#pragma unroll
        for (int jt = 0; jt < 2; ++jt) {
          int ja = jb + jt * 16 + lc;
          bool val = (ja <= qa) && (qa - ja <= WIN_);
          se[jt] = val ? sacc[jt][r] * SCALE_ : -__builtin_inff();
          cm = fmaxf(cm, se[jt]);
        }
        cm = fmaxf(cm, __shfl_xor(cm, 1));
        cm = fmaxf(cm, __shfl_xor(cm, 2));
        cm = fmaxf(cm, __shfl_xor(cm, 4));
        cm = fmaxf(cm, __shfl_xor(cm, 8));
        float mnew = fmaxf(mrow[r], cm);
        float esum = 0.f;
#pragma unroll
        for (int jt = 0; jt < 2; ++jt) {
          float e = __expf(se[jt] - mnew);
          e = (se[jt] == -__builtin_inff()) ? 0.f : e;
          pv[jt][r] = e;
          esum += e;
        }
        esum += __shfl_xor(esum, 1);
        esum += __shfl_xor(esum, 2);
        esum += __shfl_xor(esum, 4);
        esum += __shfl_xor(esum, 8);
        float rf = __expf(mrow[r] - mnew);
        rf = (mnew == -__builtin_inff()) ? 0.f : rf;
        rr[r] = rf;
        lsum[r] = lsum[r] * rf + esum;
        mrow[r] = mnew;
      }
#pragma unroll
      for (int jt = 0; jt < 2; ++jt)
#pragma unroll
        for (int r = 0; r < 4; ++r)
          Ps[w][l4 * 4 + r][jt * 16 + lc] = f2bf(pv[jt][r]);
      asm volatile("s_waitcnt lgkmcnt(0)" ::: "memory");
      __builtin_amdgcn_sched_barrier(0);
      bf16x8 ap = *reinterpret_cast<const bf16x8*>(&Ps[w][lc][l4 * 8]);
#pragma unroll
      for (int dt = 0; dt < 4; ++dt) {
        int d = dt * 16 + lc;
        int cb = (l4 * 16) ^ (((d >> 1) & 3) << 4);
        bf16x8 bv = *reinterpret_cast<const bf16x8*>(
            reinterpret_cast<char*>(Vt) + d * 64 + cb);
#pragma unroll
        for (int r = 0; r < 4; ++r) oacc[dt][r] *= rr[r];
        oacc[dt] = __builtin_amdgcn_mfma_f32_16x16x32_bf16(ap, bv, oacc[dt], 0, 0, 0);
      }
    }
  }
  float inv[4];
#pragma unroll
  for (int r = 0; r < 4; ++r) inv[r] = 1.f / lsum[r];
  size_t obase = (size_t)(b * S_ + qw0) * D_ + h * 64;
#pragma unroll
  for (int dt = 0; dt < 4; ++dt)
#pragma unroll
    for (int r = 0; r < 4; ++r)
      out[obase + (size_t)(l4 * 4 + r) * D_ + dt * 16 + lc] = f2bf(oacc[dt][r] * inv[r]);
}

// ---------------- bf16 MFMA GEMM:  C(MxN) = A(MxK) @ Bt(NxK)^T, 128x128 tile, BK=32
// EPI 0: f32 store | 1: resid + gate*v f32 | 2: bf16 store | 3: fused swiglu (interleaved cols)
DEV bf16x8 read_frag(const u16* tile, int r16, int lane) {
  int r = r16 + (lane & 15);
  int cb = ((lane >> 4) << 4) ^ (((r >> 1) & 3) << 4);
  return *reinterpret_cast<const bf16x8*>(reinterpret_cast<const char*>(tile) + r * 64 + cb);
}

DEV void stage_tile(const u16* __restrict__ src, int ld, int rowBase, int kBase,
                    u16* tile, int tid) {
#pragma unroll
  for (int c = 0; c < 2; ++c) {
    int row = c * 64 + (tid >> 2);
    int cbs = ((tid & 3) << 4) ^ (((row >> 1) & 3) << 4);
    const char* g = reinterpret_cast<const char*>(src + (size_t)(rowBase + row) * ld + kBase) + cbs;
    char* l = reinterpret_cast<char*>(tile) + c * 4096 + (tid >> 6) * 1024;
    __builtin_amdgcn_global_load_lds((gptr_t)g, (lptr_t)l, 16, 0, 0);
  }
}

template <int EPI>
__global__ __launch_bounds__(256, 2) void gemm_bt(const u16* __restrict__ A,
                                                  const u16* __restrict__ Bt,
                                                  int M, int N, int K,
                                                  void* __restrict__ Cv,
                                                  const float* __restrict__ gate,
                                                  const float* __restrict__ resid) {
  __shared__ __align__(16) u16 lds[2][2][4096];
  int tid = threadIdx.x;
  int lane = tid & 63;
  int w = tid >> 6;
  int wr = w >> 1, wc = w & 1;
  int m0 = blockIdx.y * 128;
  int n0 = blockIdx.x * 128;
  f32x4 zero = {0.f, 0.f, 0.f, 0.f};
  f32x4 acc[4][4];
#pragma unroll
  for (int i = 0; i < 4; ++i)
#pragma unroll
    for (int j = 0; j < 4; ++j) acc[i][j] = zero;
  stage_tile(A, K, m0, 0, &lds[0][0][0], tid);
  stage_tile(Bt, K, n0, 0, &lds[0][1][0], tid);
  __syncthreads();
  int nt = K >> 5;
  int cur = 0;
  for (int t = 0; t < nt; ++t) {
    if (t + 1 < nt) {
      stage_tile(A, K, m0, (t + 1) << 5, &lds[cur ^ 1][0][0], tid);
      stage_tile(Bt, K, n0, (t + 1) << 5, &lds[cur ^ 1][1][0], tid);
    }
    bf16x8 af[4], bfr[4];
#pragma unroll
    for (int i = 0; i < 4; ++i) af[i] = read_frag(&lds[cur][0][0], wr * 64 + i * 16, lane);
#pragma unroll
    for (int i = 0; i < 4; ++i) bfr[i] = read_frag(&lds[cur][1][0], wc * 64 + i * 16, lane);
#pragma unroll
    for (int i = 0; i < 4; ++i)
#pragma unroll
      for (int j = 0; j < 4; ++j)
        acc[i][j] = __builtin_amdgcn_mfma_f32_16x16x32_bf16(af[i], bfr[j], acc[i][j], 0, 0, 0);
    __syncthreads();
    cur ^= 1;
  }
  int rowB = m0 + wr * 64 + ((lane >> 4) << 2);
  if constexpr (EPI == 3) {
    // interleaved columns: group16 even = g1, odd = g3; pairs live in j and j+1 of same lane
    u16* swig = reinterpret_cast<u16*>(Cv);
    int scolB = (n0 >> 1) + wc * 32 + (lane & 15);
#pragma unroll
    for (int i = 0; i < 4; ++i)
#pragma unroll
      for (int jp = 0; jp < 2; ++jp)
#pragma unroll
        for (int jr = 0; jr < 4; ++jr) {
          int row = rowB + i * 16 + jr;
          float a = acc[i][jp * 2][jr];
          float b3 = acc[i][jp * 2 + 1][jr];
          float sv = a / (1.f + __expf(-a)) * b3;
          swig[(size_t)row * 4096 + scolB + jp * 16] = f2bf(sv);
        }
  } else {
    int colB = n0 + wc * 64 + (lane & 15);
#pragma unroll
    for (int i = 0; i < 4; ++i) {
#pragma unroll
      for (int j = 0; j < 4; ++j) {
        int col = colB + j * 16;
#pragma unroll
        for (int jr = 0; jr < 4; ++jr) {
          int row = rowB + i * 16 + jr;
          float v = acc[i][j][jr];
          size_t idx = (size_t)row * N + col;
          if constexpr (EPI == 0) {
            reinterpret_cast<float*>(Cv)[idx] = v;
          } else if constexpr (EPI == 1) {
            int bb = row >> 11;
            reinterpret_cast<float*>(Cv)[idx] = resid[idx] + gate[bb * 3072 + col] * v;
          } else {
            reinterpret_cast<u16*>(Cv)[idx] = f2bf(v);
          }
        }
      }
    }
  }
}

extern "C" void kernel_launch(void* const* d_in, const int* in_sizes, int n_in,
                              void* d_out, int out_size, void* d_ws, size_t ws_size,
                              hipStream_t stream) {
  const float* x    = (const float*)d_in[0];
  const float* rc   = (const float*)d_in[1];
  const float* rs   = (const float*)d_in[2];
  const float* cond = (const float*)d_in[3];
  const float* wq   = (const float*)d_in[4];
  const float* wk   = (const float*)d_in[5];
  const float* wv   = (const float*)d_in[6];
  const float* wo   = (const float*)d_in[7];
  const float* aaw  = (const float*)d_in[8];
  const float* aab  = (const float*)d_in[9];
  const float* afw  = (const float*)d_in[10];
  const float* afb  = (const float*)d_in[11];
  const float* w1   = (const float*)d_in[12];
  const float* w3   = (const float*)d_in[13];
  const float* w2   = (const float*)d_in[14];
  float* out = (float*)d_out;
  char* ws = (char*)d_ws;

  u16*   wt_qkv = (u16*)  (ws + 0);           // 3072x1024 bf16
  u16*   wt_o   = (u16*)  (ws + 6291456);     // 1024x1024
  u16*   wt_13  = (u16*)  (ws + 8388608);     // 8192x1024 (16-col interleaved g1/g3)
  u16*   wt_2   = (u16*)  (ws + 25165824);    // 1024x4096
  float* modf   = (float*)(ws + 33554432);    // [2 sets][B][3072]
  u16*   norm_b = (u16*)  (ws + 33603584);    // M x 1024 bf16
  u16*   attn_b = (u16*)  (ws + 41992192);    // M x 1024 bf16
  u16*   qkv_bf = (u16*)  (ws + 50380800);    // M x 3072 bf16
  float* adpart = (float*)(ws + 50380800);    // [4 sb][8 ks][3072] f32 — dead before qkv GEMM
  float* hbuf   = (float*)(ws + 117489664);   // M x 1024 f32
  u16*   swig_b = (u16*)  (ws + 134266880);   // M x 4096 bf16

  adaln_part<<<dim3(12, 8, 4), 256, 0, stream>>>(cond, aaw, afw, adpart);
  adaln_reduce<<<dim3(12, 4), 256, 0, stream>>>(adpart, aab, afb, modf);
  transpose_sq4<<<dim3(32, 32, 4), 256, 0, stream>>>(
      wq, wk, wv, wo, wt_qkv, wt_qkv + 1048576, wt_qkv + 2097152, wt_o);
  transpose_13<<<dim3(128, 32, 2), 256, 0, stream>>>(w1, w3, wt_13);
  transpose_cast<<<dim3(32, 128), 256, 0, stream>>>(w2, 4096, 1024, wt_2);

  ln_mod_kernel<<<4096, 256, 0, stream>>>(x, modf, norm_b);
  gemm_bt<2><<<dim3(24, 32), 256, 0, stream>>>(norm_b, wt_qkv, M_, 3072, 1024, qkv_bf, nullptr, nullptr);
  attn_mfma<<<dim3(32, 16, 2), 256, 0, stream>>>(qkv_bf, rc, rs, attn_b);
  gemm_bt<1><<<dim3(8, 32), 256, 0, stream>>>(attn_b, wt_o, M_, 1024, 1024, hbuf, modf + 2048, x);
  ln_mod_kernel<<<4096, 256, 0, stream>>>(hbuf, modf + 6144, norm_b);
  gemm_bt<3><<<dim3(64, 32), 256, 0, stream>>>(norm_b, wt_13, M_, 8192, 1024, swig_b, nullptr, nullptr);
  gemm_bt<1><<<dim3(8, 32), 256, 0, stream>>>(swig_b, wt_2, M_, 1024, 4096, out, modf + 6144 + 2048, hbuf);
}